// Round 6
// baseline (494.011 us; speedup 1.0000x reference)
//
#include <hip/hip_runtime.h>
#include <hip/hip_bf16.h>

#define NN 50000
#define EE 640000
#define NB 196  // ceil(NN/256)

typedef __attribute__((ext_vector_type(8))) short short8;
typedef __attribute__((ext_vector_type(4))) float f32x4;

__device__ __forceinline__ float bf2f(ushort u) {
    return __uint_as_float(((uint)u) << 16);
}
__device__ __forceinline__ ushort f2bf(float f) {
    uint b = __float_as_uint(f);
    uint r = (b + 0x7fffu + ((b >> 16) & 1u)) >> 16;
    return (ushort)r;
}
__device__ __forceinline__ ushort f2bf_rn(float f) {
    return (ushort)((__float_as_uint(f) + 0x8000u) >> 16);
}

// ---- CSR build (+ fused weight composition) -------------------------------

// blocks [0, 2500): histogram of dst. blocks [2500, 2884): weight compose.
__global__ __launch_bounds__(256) void k_hist_compose(
    const int* __restrict__ ei, int* __restrict__ counts,
    const float* __restrict__ wn_all, const float* __restrict__ aw1,
    const float* __restrict__ wle, ushort* __restrict__ wcT) {
    if (blockIdx.x < 2500) {
        int e = blockIdx.x * 256 + threadIdx.x;
        if (e < EE) atomicAdd(&counts[ei[EE + e]], 1);
        return;
    }
    const int bb = blockIdx.x - 2500;
    const int l = bb >> 7;
    const int k = bb & 127;
    const int t = threadIdx.x;
    const float* wn = wn_all + (l * 128 + k) * 128;
    float acc = 0.f;
    for (int c = 0; c < 128; ++c) {
        float cat;
        if (t < 128)
            cat = aw1[(l * 256 + ((t & 64) << 1) + c) * 64 + (t & 63)];
        else
            cat = wle[(l * 130 + c) * 128 + (t - 128)];
        acc += wn[c] * cat;
    }
    wcT[(l * 256 + t) * 128 + k] = f2bf(acc);
}

__global__ __launch_bounds__(256) void k_scan_a(const int* __restrict__ counts,
                                                int* __restrict__ bsum) {
    int i = blockIdx.x * 256 + threadIdx.x;
    int v = (i < NN) ? counts[i] : 0;
    #pragma unroll
    for (int o = 32; o > 0; o >>= 1) v += __shfl_xor(v, o);
    __shared__ int ws[4];
    if ((threadIdx.x & 63) == 0) ws[threadIdx.x >> 6] = v;
    __syncthreads();
    if (threadIdx.x == 0) bsum[blockIdx.x] = ws[0] + ws[1] + ws[2] + ws[3];
}

__global__ __launch_bounds__(256) void k_scan_b(const int* __restrict__ bsum,
                                                int* __restrict__ boff,
                                                int* __restrict__ offs) {
    const int t = threadIdx.x;
    const int lane = t & 63, wave = t >> 6;
    int v = (t < NB) ? bsum[t] : 0;
    int x = v;
    #pragma unroll
    for (int o = 1; o < 64; o <<= 1) {
        int y = __shfl_up(x, o);
        if (lane >= o) x += y;
    }
    __shared__ int ws[4];
    if (lane == 63) ws[wave] = x;
    __syncthreads();
    int add = 0;
    for (int w = 0; w < wave; ++w) add += ws[w];
    x += add;
    if (t < NB) boff[t] = x - v;
    if (t == 255) offs[NN] = x;
}

__global__ __launch_bounds__(256) void k_scan_c(const int* __restrict__ counts,
                                                const int* __restrict__ boff,
                                                int* __restrict__ offs,
                                                int* __restrict__ cursor) {
    int i = blockIdx.x * 256 + threadIdx.x;
    const int lane = threadIdx.x & 63, wave = threadIdx.x >> 6;
    int v = (i < NN) ? counts[i] : 0;
    int x = v;
    #pragma unroll
    for (int o = 1; o < 64; o <<= 1) {
        int y = __shfl_up(x, o);
        if (lane >= o) x += y;
    }
    __shared__ int ws[4];
    if (lane == 63) ws[wave] = x;
    __syncthreads();
    int add = boff[blockIdx.x];
    for (int w = 0; w < wave; ++w) add += ws[w];
    int ex = add + x - v;
    if (i < NN) {
        offs[i] = ex;
        cursor[i] = ex;
    }
}

__global__ __launch_bounds__(256) void k_scatter(const int* __restrict__ ei,
                                                 const float* __restrict__ ea,
                                                 int* __restrict__ cursor,
                                                 uint2* __restrict__ adj,
                                                 uint* __restrict__ adst) {
    int e = blockIdx.x * 256 + threadIdx.x;
    if (e >= EE) return;
    int d = ei[EE + e];
    int pos = atomicAdd(&cursor[d], 1);
    ushort lo = f2bf(ea[2 * e]);
    ushort hi = f2bf(ea[2 * e + 1]);
    adj[pos] = make_uint2((uint)ei[e], ((uint)hi << 16) | (uint)lo);
    adst[pos] = (uint)d;
}

// ---- K1: pqr = x @ Wc   [N,128]x[128,256] -> bf16 [N,256] -----------------

__global__ __launch_bounds__(256) void k1_gemm(const float* __restrict__ xin,
                                               const ushort* __restrict__ wcT,
                                               ushort* __restrict__ pqr) {
    const int wave = threadIdx.x >> 6;
    const int lane = threadIdx.x & 63;
    const int r0 = blockIdx.x * 16;
    const int c0 = wave * 64;
    const int lrow = lane & 15;
    const int kg = lane >> 4;

    const float* xrow = xin + (r0 + lrow) * 128;
    short8 a[4];
    #pragma unroll
    for (int s = 0; s < 4; ++s) {
        const float* px = xrow + s * 32 + kg * 8;
        float4 u = *(const float4*)(px);
        float4 v = *(const float4*)(px + 4);
        short8 av;
        av[0] = (short)f2bf(u.x); av[1] = (short)f2bf(u.y);
        av[2] = (short)f2bf(u.z); av[3] = (short)f2bf(u.w);
        av[4] = (short)f2bf(v.x); av[5] = (short)f2bf(v.y);
        av[6] = (short)f2bf(v.z); av[7] = (short)f2bf(v.w);
        a[s] = av;
    }

    f32x4 acc[4] = {};
    #pragma unroll
    for (int t = 0; t < 4; ++t) {
        const int col = c0 + t * 16 + lrow;
        #pragma unroll
        for (int s = 0; s < 4; ++s) {
            short8 b = *(const short8*)(wcT + col * 128 + s * 32 + kg * 8);
            acc[t] = __builtin_amdgcn_mfma_f32_16x16x32_bf16(a[s], b, acc[t], 0, 0, 0);
        }
    }
    #pragma unroll
    for (int t = 0; t < 4; ++t) {
        const int col = c0 + t * 16 + lrow;
        #pragma unroll
        for (int j = 0; j < 4; ++j) {
            pqr[(r0 + kg * 4 + j) * 256 + col] = f2bf(acc[t][j]);
        }
    }
}

// ---- K_att: edge-parallel attention scores via MFMA -----------------------
// One wave = 64 edges = 4 MFMA tiles sharing one B fragment (col0 = w2).

__global__ __launch_bounds__(256) void k_att(const uint2* __restrict__ adj,
                                             const uint* __restrict__ adst,
                                             const ushort* __restrict__ pqr,
                                             const float* __restrict__ b1v,
                                             const float* __restrict__ w2v,
                                             const float* __restrict__ b2v,
                                             float* __restrict__ attv) {
    const int lane = threadIdx.x & 63;
    const int e0 = blockIdx.x * 256 + (threadIdx.x >> 6) * 64;
    const int row = lane & 15;
    const int kg = lane >> 4;
    const float b2 = b2v[0];

    short8 bv0, bv1;
    const bool col0 = (row == 0);
    #pragma unroll
    for (int j = 0; j < 8; ++j) {
        bv0[j] = (short)f2bf(col0 ? w2v[kg * 8 + j] : 0.f);
        bv1[j] = (short)f2bf(col0 ? w2v[32 + kg * 8 + j] : 0.f);
    }

    uint srcs[4], dsts[4];
    #pragma unroll
    for (int t = 0; t < 4; ++t) {
        const int eidx = e0 + t * 16 + row;
        srcs[t] = adj[eidx].x;
        dsts[t] = adst[eidx];
    }

    f32x4 acc[4] = {};
    #pragma unroll
    for (int h = 0; h < 2; ++h) {
        const int cb = 32 * h + kg * 8;
        float4 bA = *(const float4*)(b1v + cb);
        float4 bB = *(const float4*)(b1v + cb + 4);
        const short8 bfrag = h ? bv1 : bv0;
        #pragma unroll
        for (int t = 0; t < 4; ++t) {
            short8 qv = *(const short8*)(pqr + (size_t)srcs[t] * 256 + 64 + cb);
            short8 pv = *(const short8*)(pqr + (size_t)dsts[t] * 256 + cb);
            short8 av;
            #pragma unroll
            for (int j = 0; j < 8; ++j) {
                float bb = (j < 4) ? ((const float*)&bA)[j] : ((const float*)&bB)[j - 4];
                float v = bf2f((ushort)qv[j]) + bf2f((ushort)pv[j]) + bb;
                av[j] = (short)f2bf_rn(fmaxf(v, 0.f));
            }
            acc[t] = __builtin_amdgcn_mfma_f32_16x16x32_bf16(av, bfrag, acc[t], 0, 0, 0);
        }
    }
    if (row == 0) {
        #pragma unroll
        for (int t = 0; t < 4; ++t) {
            float4 o;
            #pragma unroll
            for (int j = 0; j < 4; ++j) {
                float s = acc[t][j] + b2;
                ((float*)&o)[j] = 1.f / (1.f + __expf(-s));
            }
            *(float4*)(attv + e0 + t * 16 + kg * 4) = o;
        }
    }
}

// ---- K_msg: 2 waves per node, scalar-stage pipeline, LDS combine ----------
// 512 threads = 8 waves = 4 nodes; wave (s4,half) handles half of node s4's
// CSR range. Pipeline: meta 4-ahead, r-gather 2-ahead; named stage regs.

__global__ __launch_bounds__(512) void k_msg(
    const int* __restrict__ offs, const uint2* __restrict__ adj,
    const float* __restrict__ attv, const ushort* __restrict__ pqr,
    const float* __restrict__ xin, const float* __restrict__ web,
    const float* __restrict__ biasv, const float* __restrict__ gammav,
    const float* __restrict__ betav, float* __restrict__ xout, int do_relu) {
    const int lane = threadIdx.x & 63;
    const int wave = threadIdx.x >> 6;   // 0..7
    const int s4 = wave & 3;
    const int half = wave >> 2;          // 0 or 1
    const int n = blockIdx.x * 4 + s4;
    const int c0 = 2 * lane;

    const int eb = offs[n], ee = offs[n + 1];
    const int cnt = ee - eb;
    const int h0 = (cnt + 1) >> 1;
    const int ms = eb + half * h0;
    const int me = half ? ee : (eb + h0);

    float acc0 = 0.f, acc1 = 0.f, sE0 = 0.f, sE1 = 0.f;
    if (ms < me) {
        const ushort* rp = pqr + 128 + c0;
        // prologue: meta stages 0..3 (clamped, att=0 when OOR), r 0..1
        int j1 = ms + 1 < me ? ms + 1 : ms;
        int j2 = ms + 2 < me ? ms + 2 : ms;
        int j3 = ms + 3 < me ? ms + 3 : ms;
        uint2 m0 = adj[ms], m1 = adj[j1], m2 = adj[j2], m3 = adj[j3];
        float a0 = attv[ms];
        float a1 = (ms + 1 < me) ? attv[j1] : 0.f;
        float a2 = (ms + 2 < me) ? attv[j2] : 0.f;
        float a3 = (ms + 3 < me) ? attv[j3] : 0.f;
        uint r0 = *(const uint*)(rp + (size_t)m0.x * 256);
        uint r1 = *(const uint*)(rp + (size_t)m1.x * 256);
        for (int i = ms; i < me; ++i) {
            const int j4 = i + 4;
            const int j4c = j4 < me ? j4 : ms;
            const uint2 m4 = adj[j4c];
            const float a4 = (j4 < me) ? attv[j4c] : 0.f;
            const uint r2 = *(const uint*)(rp + (size_t)m2.x * 256);
            acc0 = fmaf(a0, __uint_as_float(r0 << 16), acc0);
            acc1 = fmaf(a0, __uint_as_float(r0 & 0xffff0000u), acc1);
            sE0  = fmaf(a0, __uint_as_float(m0.y << 16), sE0);
            sE1  = fmaf(a0, __uint_as_float(m0.y & 0xffff0000u), sE1);
            m0 = m1; a0 = a1; r0 = r1;
            m1 = m2; a1 = a2; r1 = r2;
            m2 = m3; a2 = a3;
            m3 = m4; a3 = a4;
        }
    }

    __shared__ float4 lds[4][64];
    if (half) {
        float4 t; t.x = acc0; t.y = acc1; t.z = sE0; t.w = sE1;
        lds[s4][lane] = t;
    }
    __syncthreads();
    if (half) return;

    {
        float4 t = lds[s4][lane];
        acc0 += t.x; acc1 += t.y; sE0 += t.z; sE1 += t.w;
    }
    const float web00 = web[c0], web01 = web[c0 + 1];
    const float web10 = web[128 + c0], web11 = web[128 + c0 + 1];
    acc0 += sE0 * web00 + sE1 * web10;
    acc1 += sE0 * web01 + sE1 * web11;

    const float2 bi = *(const float2*)(biasv + c0);
    float v0 = acc0 + bi.x;
    float v1 = acc1 + bi.y;
    float sm = v0 + v1, sq = v0 * v0 + v1 * v1;
    #pragma unroll
    for (int o = 32; o > 0; o >>= 1) {
        sm += __shfl_xor(sm, o);
        sq += __shfl_xor(sq, o);
    }
    const float mean = sm * (1.f / 128.f);
    const float var = sq * (1.f / 128.f) - mean * mean;
    const float inv = rsqrtf(var + 1e-5f);
    const float2 ga = *(const float2*)(gammav + c0);
    const float2 be = *(const float2*)(betav + c0);
    float y0 = (v0 - mean) * inv * ga.x + be.x;
    float y1 = (v1 - mean) * inv * ga.y + be.y;
    if (do_relu) { y0 = fmaxf(y0, 0.f); y1 = fmaxf(y1, 0.f); }
    const float2 xr = *(const float2*)(xin + (size_t)n * 128 + c0);
    y0 += xr.x;
    y1 += xr.y;
    float2 o2; o2.x = y0; o2.y = y1;
    *(float2*)(xout + (size_t)n * 128 + c0) = o2;
}

// ---------------------------------------------------------------------------

extern "C" void kernel_launch(void* const* d_in, const int* in_sizes, int n_in,
                              void* d_out, int out_size, void* d_ws, size_t ws_size,
                              hipStream_t stream) {
    const float* x   = (const float*)d_in[0];
    const int*   ei  = (const int*)d_in[1];
    const float* ea  = (const float*)d_in[2];
    const float* wn  = (const float*)d_in[3];
    const float* wle = (const float*)d_in[4];
    const float* aw1 = (const float*)d_in[5];
    const float* ab1 = (const float*)d_in[6];
    const float* aw2 = (const float*)d_in[7];
    const float* ab2 = (const float*)d_in[8];
    const float* bia = (const float*)d_in[9];
    const float* gam = (const float*)d_in[10];
    const float* bet = (const float*)d_in[11];

    char* w = (char*)d_ws;
    size_t o = 0;
    auto alloc = [&](size_t bytes) {
        char* p = w + o;
        o = (o + bytes + 255) & ~(size_t)255;
        return p;
    };
    int*    counts = (int*)alloc((size_t)NN * 4);
    int*    offs   = (int*)alloc((size_t)(NN + 1) * 4);
    int*    cursor = (int*)alloc((size_t)NN * 4);
    int*    bsum   = (int*)alloc((size_t)NB * 4);
    int*    boff   = (int*)alloc((size_t)NB * 4);
    uint2*  adj    = (uint2*)alloc((size_t)EE * 8);
    uint*   adst   = (uint*)alloc((size_t)EE * 4);
    float*  attv   = (float*)alloc((size_t)EE * 4);
    ushort* wcT    = (ushort*)alloc((size_t)3 * 256 * 128 * 2);
    ushort* pqr    = (ushort*)alloc((size_t)NN * 256 * 2);
    float*  xb1    = (float*)alloc((size_t)NN * 128 * 4);
    float*  xb2    = (float*)alloc((size_t)NN * 128 * 4);

    hipMemsetAsync(counts, 0, (size_t)NN * 4, stream);
    k_hist_compose<<<2500 + 384, 256, 0, stream>>>(ei, counts, wn, aw1, wle, wcT);
    k_scan_a<<<NB, 256, 0, stream>>>(counts, bsum);
    k_scan_b<<<1, 256, 0, stream>>>(bsum, boff, offs);
    k_scan_c<<<NB, 256, 0, stream>>>(counts, boff, offs, cursor);
    k_scatter<<<(EE + 255) / 256, 256, 0, stream>>>(ei, ea, cursor, adj, adst);

    const float* xi = x;
    float* xo = xb1;
    for (int l = 0; l < 3; ++l) {
        k1_gemm<<<NN / 16, 256, 0, stream>>>(xi, wcT + (size_t)l * 256 * 128, pqr);
        k_att<<<EE / 256, 256, 0, stream>>>(adj, adst, pqr,
                                            ab1 + l * 64, aw2 + l * 64, ab2 + l, attv);
        const bool last = (l == 2);
        float* out_ptr = last ? (float*)d_out : xo;
        k_msg<<<NN / 4, 512, 0, stream>>>(
            offs, adj, attv, pqr, xi,
            wle + ((size_t)l * 130 + 128) * 128,
            bia + l * 128, gam + l * 128, bet + l * 128,
            out_ptr, last ? 0 : 1);
        xi = out_ptr;
        xo = (l == 0) ? xb2 : xb1;
    }
}

// Round 7
// 390.153 us; speedup vs baseline: 1.2662x; 1.2662x over previous
//
#include <hip/hip_runtime.h>
#include <hip/hip_bf16.h>

#define NN 50000
#define EE 640000
#define NB 196  // ceil(NN/256)

typedef __attribute__((ext_vector_type(8))) short short8;
typedef __attribute__((ext_vector_type(4))) float f32x4;

__device__ __forceinline__ float bf2f(ushort u) {
    return __uint_as_float(((uint)u) << 16);
}
__device__ __forceinline__ ushort f2bf(float f) {
    uint b = __float_as_uint(f);
    uint r = (b + 0x7fffu + ((b >> 16) & 1u)) >> 16;
    return (ushort)r;
}
__device__ __forceinline__ ushort f2bf_rn(float f) {
    return (ushort)((__float_as_uint(f) + 0x8000u) >> 16);
}

// ---- CSR build (+ fused weight composition) -------------------------------

// blocks [0, 2500): histogram of dst. blocks [2500, 2884): weight compose.
__global__ __launch_bounds__(256) void k_hist_compose(
    const int* __restrict__ ei, int* __restrict__ counts,
    const float* __restrict__ wn_all, const float* __restrict__ aw1,
    const float* __restrict__ wle, ushort* __restrict__ wcT) {
    if (blockIdx.x < 2500) {
        int e = blockIdx.x * 256 + threadIdx.x;
        if (e < EE) atomicAdd(&counts[ei[EE + e]], 1);
        return;
    }
    const int bb = blockIdx.x - 2500;
    const int l = bb >> 7;
    const int k = bb & 127;
    const int t = threadIdx.x;
    const float* wn = wn_all + (l * 128 + k) * 128;
    float acc = 0.f;
    for (int c = 0; c < 128; ++c) {
        float cat;
        if (t < 128)
            cat = aw1[(l * 256 + ((t & 64) << 1) + c) * 64 + (t & 63)];
        else
            cat = wle[(l * 130 + c) * 128 + (t - 128)];
        acc += wn[c] * cat;
    }
    wcT[(l * 256 + t) * 128 + k] = f2bf(acc);
}

__global__ __launch_bounds__(256) void k_scan_a(const int* __restrict__ counts,
                                                int* __restrict__ bsum) {
    int i = blockIdx.x * 256 + threadIdx.x;
    int v = (i < NN) ? counts[i] : 0;
    #pragma unroll
    for (int o = 32; o > 0; o >>= 1) v += __shfl_xor(v, o);
    __shared__ int ws[4];
    if ((threadIdx.x & 63) == 0) ws[threadIdx.x >> 6] = v;
    __syncthreads();
    if (threadIdx.x == 0) bsum[blockIdx.x] = ws[0] + ws[1] + ws[2] + ws[3];
}

__global__ __launch_bounds__(256) void k_scan_b(const int* __restrict__ bsum,
                                                int* __restrict__ boff,
                                                int* __restrict__ offs) {
    const int t = threadIdx.x;
    const int lane = t & 63, wave = t >> 6;
    int v = (t < NB) ? bsum[t] : 0;
    int x = v;
    #pragma unroll
    for (int o = 1; o < 64; o <<= 1) {
        int y = __shfl_up(x, o);
        if (lane >= o) x += y;
    }
    __shared__ int ws[4];
    if (lane == 63) ws[wave] = x;
    __syncthreads();
    int add = 0;
    for (int w = 0; w < wave; ++w) add += ws[w];
    x += add;
    if (t < NB) boff[t] = x - v;
    if (t == 255) offs[NN] = x;
}

__global__ __launch_bounds__(256) void k_scan_c(const int* __restrict__ counts,
                                                const int* __restrict__ boff,
                                                int* __restrict__ offs,
                                                int* __restrict__ cursor) {
    int i = blockIdx.x * 256 + threadIdx.x;
    const int lane = threadIdx.x & 63, wave = threadIdx.x >> 6;
    int v = (i < NN) ? counts[i] : 0;
    int x = v;
    #pragma unroll
    for (int o = 1; o < 64; o <<= 1) {
        int y = __shfl_up(x, o);
        if (lane >= o) x += y;
    }
    __shared__ int ws[4];
    if (lane == 63) ws[wave] = x;
    __syncthreads();
    int add = boff[blockIdx.x];
    for (int w = 0; w < wave; ++w) add += ws[w];
    int ex = add + x - v;
    if (i < NN) {
        offs[i] = ex;
        cursor[i] = ex;
    }
}

// adj4 = {src, ea_bf16x2, att(f32, filled by k_att), dst}
__global__ __launch_bounds__(256) void k_scatter(const int* __restrict__ ei,
                                                 const float* __restrict__ ea,
                                                 int* __restrict__ cursor,
                                                 uint4* __restrict__ adj4) {
    int e = blockIdx.x * 256 + threadIdx.x;
    if (e >= EE) return;
    int d = ei[EE + e];
    int pos = atomicAdd(&cursor[d], 1);
    ushort lo = f2bf(ea[2 * e]);
    ushort hi = f2bf(ea[2 * e + 1]);
    adj4[pos] = make_uint4((uint)ei[e], ((uint)hi << 16) | (uint)lo, 0u, (uint)d);
}

// ---- K1: pqr = x @ Wc   [N,128]x[128,256] -> bf16 [N,256] -----------------

__global__ __launch_bounds__(256) void k1_gemm(const float* __restrict__ xin,
                                               const ushort* __restrict__ wcT,
                                               ushort* __restrict__ pqr) {
    const int wave = threadIdx.x >> 6;
    const int lane = threadIdx.x & 63;
    const int r0 = blockIdx.x * 16;
    const int c0 = wave * 64;
    const int lrow = lane & 15;
    const int kg = lane >> 4;

    const float* xrow = xin + (r0 + lrow) * 128;
    short8 a[4];
    #pragma unroll
    for (int s = 0; s < 4; ++s) {
        const float* px = xrow + s * 32 + kg * 8;
        float4 u = *(const float4*)(px);
        float4 v = *(const float4*)(px + 4);
        short8 av;
        av[0] = (short)f2bf(u.x); av[1] = (short)f2bf(u.y);
        av[2] = (short)f2bf(u.z); av[3] = (short)f2bf(u.w);
        av[4] = (short)f2bf(v.x); av[5] = (short)f2bf(v.y);
        av[6] = (short)f2bf(v.z); av[7] = (short)f2bf(v.w);
        a[s] = av;
    }

    f32x4 acc[4] = {};
    #pragma unroll
    for (int t = 0; t < 4; ++t) {
        const int col = c0 + t * 16 + lrow;
        #pragma unroll
        for (int s = 0; s < 4; ++s) {
            short8 b = *(const short8*)(wcT + col * 128 + s * 32 + kg * 8);
            acc[t] = __builtin_amdgcn_mfma_f32_16x16x32_bf16(a[s], b, acc[t], 0, 0, 0);
        }
    }
    #pragma unroll
    for (int t = 0; t < 4; ++t) {
        const int col = c0 + t * 16 + lrow;
        #pragma unroll
        for (int j = 0; j < 4; ++j) {
            pqr[(r0 + kg * 4 + j) * 256 + col] = f2bf(acc[t][j]);
        }
    }
}

// ---- K_att: edge-parallel attention scores via MFMA -----------------------
// One wave = 64 edges = 4 MFMA tiles sharing one B fragment (col0 = w2).
// Reads adj4 {src,_,_,dst}; writes att into adj4[.].z (4B scattered stores).

__global__ __launch_bounds__(256) void k_att(uint4* __restrict__ adj4,
                                             const ushort* __restrict__ pqr,
                                             const float* __restrict__ b1v,
                                             const float* __restrict__ w2v,
                                             const float* __restrict__ b2v) {
    const int lane = threadIdx.x & 63;
    const int e0 = blockIdx.x * 256 + (threadIdx.x >> 6) * 64;
    const int row = lane & 15;
    const int kg = lane >> 4;
    const float b2 = b2v[0];

    short8 bv0, bv1;
    const bool col0 = (row == 0);
    #pragma unroll
    for (int j = 0; j < 8; ++j) {
        bv0[j] = (short)f2bf(col0 ? w2v[kg * 8 + j] : 0.f);
        bv1[j] = (short)f2bf(col0 ? w2v[32 + kg * 8 + j] : 0.f);
    }

    uint srcs[4], dsts[4];
    #pragma unroll
    for (int t = 0; t < 4; ++t) {
        const uint4 m = adj4[e0 + t * 16 + row];
        srcs[t] = m.x;
        dsts[t] = m.w;
    }

    f32x4 acc[4] = {};
    #pragma unroll
    for (int h = 0; h < 2; ++h) {
        const int cb = 32 * h + kg * 8;
        float4 bA = *(const float4*)(b1v + cb);
        float4 bB = *(const float4*)(b1v + cb + 4);
        const short8 bfrag = h ? bv1 : bv0;
        #pragma unroll
        for (int t = 0; t < 4; ++t) {
            short8 qv = *(const short8*)(pqr + (size_t)srcs[t] * 256 + 64 + cb);
            short8 pv = *(const short8*)(pqr + (size_t)dsts[t] * 256 + cb);
            short8 av;
            #pragma unroll
            for (int j = 0; j < 8; ++j) {
                float bb = (j < 4) ? ((const float*)&bA)[j] : ((const float*)&bB)[j - 4];
                float v = bf2f((ushort)qv[j]) + bf2f((ushort)pv[j]) + bb;
                av[j] = (short)f2bf_rn(fmaxf(v, 0.f));
            }
            acc[t] = __builtin_amdgcn_mfma_f32_16x16x32_bf16(av, bfrag, acc[t], 0, 0, 0);
        }
    }
    if (row == 0) {
        #pragma unroll
        for (int t = 0; t < 4; ++t) {
            #pragma unroll
            for (int j = 0; j < 4; ++j) {
                float s = acc[t][j] + b2;
                float att = 1.f / (1.f + __expf(-s));
                *(float*)((char*)(adj4 + e0 + t * 16 + kg * 4 + j) + 8) = att;
            }
        }
    }
}

// ---- K_msg: 1 wave/node, A/B-quad pipeline, zero rotation -----------------
// Per edge: ONE uint4 meta load + ONE 4B gather + 4 FMA. Tail handled by
// validity-select on att (wave-uniform cmp) against a zeroed 64-entry pad.

#define CONS(MM, RR, JJ)                                              \
    {                                                                 \
        const float a_ = ((JJ) < ee) ? __uint_as_float((MM).z) : 0.f; \
        acc0 = fmaf(a_, __uint_as_float((RR) << 16), acc0);           \
        acc1 = fmaf(a_, __uint_as_float((RR) & 0xffff0000u), acc1);   \
        sE0  = fmaf(a_, __uint_as_float((MM).y << 16), sE0);          \
        sE1  = fmaf(a_, __uint_as_float((MM).y & 0xffff0000u), sE1);  \
    }

#define LOADQ(M0, M1, M2, M3, R0, R1, R2, R3, BASE)          \
    {                                                        \
        M0 = adj4[(BASE)];                                   \
        M1 = adj4[(BASE) + 1];                               \
        M2 = adj4[(BASE) + 2];                               \
        M3 = adj4[(BASE) + 3];                               \
        R0 = *(const uint*)(rp + (size_t)M0.x * 256);        \
        R1 = *(const uint*)(rp + (size_t)M1.x * 256);        \
        R2 = *(const uint*)(rp + (size_t)M2.x * 256);        \
        R3 = *(const uint*)(rp + (size_t)M3.x * 256);        \
    }

__global__ __launch_bounds__(256) void k_msg(
    const int* __restrict__ offs, const uint4* __restrict__ adj4,
    const ushort* __restrict__ pqr, const float* __restrict__ xin,
    const float* __restrict__ web, const float* __restrict__ biasv,
    const float* __restrict__ gammav, const float* __restrict__ betav,
    float* __restrict__ xout, int do_relu) {
    const int lane = threadIdx.x & 63;
    const int n = blockIdx.x * 4 + (threadIdx.x >> 6);
    const int c0 = 2 * lane;

    const int eb = __builtin_amdgcn_readfirstlane(offs[n]);
    const int ee = __builtin_amdgcn_readfirstlane(offs[n + 1]);

    float acc0 = 0.f, acc1 = 0.f, sE0 = 0.f, sE1 = 0.f;
    if (eb < ee) {
        const ushort* rp = pqr + 128 + c0;
        uint4 a0, a1, a2, a3, b0, b1, b2, b3;
        uint ra0, ra1, ra2, ra3, rb0, rb1, rb2, rb3;
        LOADQ(a0, a1, a2, a3, ra0, ra1, ra2, ra3, eb);
        LOADQ(b0, b1, b2, b3, rb0, rb1, rb2, rb3, eb + 4);
        int j = eb;
        for (; j + 8 < ee; j += 8) {
            CONS(a0, ra0, j) CONS(a1, ra1, j + 1)
            CONS(a2, ra2, j + 2) CONS(a3, ra3, j + 3)
            LOADQ(a0, a1, a2, a3, ra0, ra1, ra2, ra3, j + 8);
            CONS(b0, rb0, j + 4) CONS(b1, rb1, j + 5)
            CONS(b2, rb2, j + 6) CONS(b3, rb3, j + 7)
            LOADQ(b0, b1, b2, b3, rb0, rb1, rb2, rb3, j + 12);
        }
        CONS(a0, ra0, j) CONS(a1, ra1, j + 1)
        CONS(a2, ra2, j + 2) CONS(a3, ra3, j + 3)
        CONS(b0, rb0, j + 4) CONS(b1, rb1, j + 5)
        CONS(b2, rb2, j + 6) CONS(b3, rb3, j + 7)
    }

    const float web00 = web[c0], web01 = web[c0 + 1];
    const float web10 = web[128 + c0], web11 = web[128 + c0 + 1];
    acc0 += sE0 * web00 + sE1 * web10;
    acc1 += sE0 * web01 + sE1 * web11;

    const float2 bi = *(const float2*)(biasv + c0);
    float v0 = acc0 + bi.x;
    float v1 = acc1 + bi.y;
    float sm = v0 + v1, sq = v0 * v0 + v1 * v1;
    #pragma unroll
    for (int o = 32; o > 0; o >>= 1) {
        sm += __shfl_xor(sm, o);
        sq += __shfl_xor(sq, o);
    }
    const float mean = sm * (1.f / 128.f);
    const float var = sq * (1.f / 128.f) - mean * mean;
    const float inv = rsqrtf(var + 1e-5f);
    const float2 ga = *(const float2*)(gammav + c0);
    const float2 be = *(const float2*)(betav + c0);
    float y0 = (v0 - mean) * inv * ga.x + be.x;
    float y1 = (v1 - mean) * inv * ga.y + be.y;
    if (do_relu) { y0 = fmaxf(y0, 0.f); y1 = fmaxf(y1, 0.f); }
    const float2 xr = *(const float2*)(xin + (size_t)n * 128 + c0);
    y0 += xr.x;
    y1 += xr.y;
    float2 o2; o2.x = y0; o2.y = y1;
    *(float2*)(xout + (size_t)n * 128 + c0) = o2;
}

// ---------------------------------------------------------------------------

extern "C" void kernel_launch(void* const* d_in, const int* in_sizes, int n_in,
                              void* d_out, int out_size, void* d_ws, size_t ws_size,
                              hipStream_t stream) {
    const float* x   = (const float*)d_in[0];
    const int*   ei  = (const int*)d_in[1];
    const float* ea  = (const float*)d_in[2];
    const float* wn  = (const float*)d_in[3];
    const float* wle = (const float*)d_in[4];
    const float* aw1 = (const float*)d_in[5];
    const float* ab1 = (const float*)d_in[6];
    const float* aw2 = (const float*)d_in[7];
    const float* ab2 = (const float*)d_in[8];
    const float* bia = (const float*)d_in[9];
    const float* gam = (const float*)d_in[10];
    const float* bet = (const float*)d_in[11];

    char* w = (char*)d_ws;
    size_t o = 0;
    auto alloc = [&](size_t bytes) {
        char* p = w + o;
        o = (o + bytes + 255) & ~(size_t)255;
        return p;
    };
    int*    counts = (int*)alloc((size_t)NN * 4);
    int*    offs   = (int*)alloc((size_t)(NN + 1) * 4);
    int*    cursor = (int*)alloc((size_t)NN * 4);
    int*    bsum   = (int*)alloc((size_t)NB * 4);
    int*    boff   = (int*)alloc((size_t)NB * 4);
    uint4*  adj4   = (uint4*)alloc((size_t)(EE + 64) * 16);
    ushort* wcT    = (ushort*)alloc((size_t)3 * 256 * 128 * 2);
    ushort* pqr    = (ushort*)alloc((size_t)NN * 256 * 2);
    float*  xb1    = (float*)alloc((size_t)NN * 128 * 4);
    float*  xb2    = (float*)alloc((size_t)NN * 128 * 4);

    hipMemsetAsync(counts, 0, (size_t)NN * 4, stream);
    hipMemsetAsync(adj4 + EE, 0, (size_t)64 * 16, stream);
    k_hist_compose<<<2500 + 384, 256, 0, stream>>>(ei, counts, wn, aw1, wle, wcT);
    k_scan_a<<<NB, 256, 0, stream>>>(counts, bsum);
    k_scan_b<<<1, 256, 0, stream>>>(bsum, boff, offs);
    k_scan_c<<<NB, 256, 0, stream>>>(counts, boff, offs, cursor);
    k_scatter<<<(EE + 255) / 256, 256, 0, stream>>>(ei, ea, cursor, adj4);

    const float* xi = x;
    float* xo = xb1;
    for (int l = 0; l < 3; ++l) {
        k1_gemm<<<NN / 16, 256, 0, stream>>>(xi, wcT + (size_t)l * 256 * 128, pqr);
        k_att<<<EE / 256, 256, 0, stream>>>(adj4, pqr,
                                            ab1 + l * 64, aw2 + l * 64, ab2 + l);
        const bool last = (l == 2);
        float* out_ptr = last ? (float*)d_out : xo;
        k_msg<<<NN / 4, 256, 0, stream>>>(
            offs, adj4, pqr, xi,
            wle + ((size_t)l * 130 + 128) * 128,
            bia + l * 128, gam + l * 128, bet + l * 128,
            out_ptr, last ? 0 : 1);
        xi = out_ptr;
        xo = (l == 0) ? xb2 : xb1;
    }
}

// Round 8
// 349.082 us; speedup vs baseline: 1.4152x; 1.1177x over previous
//
#include <hip/hip_runtime.h>
#include <hip/hip_bf16.h>

#define NN 50000
#define EE 640000
#define NB 196  // ceil(NN/256)

typedef __attribute__((ext_vector_type(8))) short short8;
typedef __attribute__((ext_vector_type(4))) float f32x4;

__device__ __forceinline__ float bf2f(ushort u) {
    return __uint_as_float(((uint)u) << 16);
}
__device__ __forceinline__ ushort f2bf(float f) {
    uint b = __float_as_uint(f);
    uint r = (b + 0x7fffu + ((b >> 16) & 1u)) >> 16;
    return (ushort)r;
}
__device__ __forceinline__ ushort f2bf_rn(float f) {
    return (ushort)((__float_as_uint(f) + 0x8000u) >> 16);
}

// ---- CSR build (+ fused weight composition) -------------------------------

// blocks [0, 2500): histogram of dst. blocks [2500, 2884): weight compose.
__global__ __launch_bounds__(256) void k_hist_compose(
    const int* __restrict__ ei, int* __restrict__ counts,
    const float* __restrict__ wn_all, const float* __restrict__ aw1,
    const float* __restrict__ wle, ushort* __restrict__ wcT) {
    if (blockIdx.x < 2500) {
        int e = blockIdx.x * 256 + threadIdx.x;
        if (e < EE) atomicAdd(&counts[ei[EE + e]], 1);
        return;
    }
    const int bb = blockIdx.x - 2500;
    const int l = bb >> 7;
    const int k = bb & 127;
    const int t = threadIdx.x;
    const float* wn = wn_all + (l * 128 + k) * 128;
    float acc = 0.f;
    for (int c = 0; c < 128; ++c) {
        float cat;
        if (t < 128)
            cat = aw1[(l * 256 + ((t & 64) << 1) + c) * 64 + (t & 63)];
        else
            cat = wle[(l * 130 + c) * 128 + (t - 128)];
        acc += wn[c] * cat;
    }
    wcT[(l * 256 + t) * 128 + k] = f2bf(acc);
}

__global__ __launch_bounds__(256) void k_scan_a(const int* __restrict__ counts,
                                                int* __restrict__ bsum) {
    int i = blockIdx.x * 256 + threadIdx.x;
    int v = (i < NN) ? counts[i] : 0;
    #pragma unroll
    for (int o = 32; o > 0; o >>= 1) v += __shfl_xor(v, o);
    __shared__ int ws[4];
    if ((threadIdx.x & 63) == 0) ws[threadIdx.x >> 6] = v;
    __syncthreads();
    if (threadIdx.x == 0) bsum[blockIdx.x] = ws[0] + ws[1] + ws[2] + ws[3];
}

__global__ __launch_bounds__(256) void k_scan_b(const int* __restrict__ bsum,
                                                int* __restrict__ boff,
                                                int* __restrict__ offs) {
    const int t = threadIdx.x;
    const int lane = t & 63, wave = t >> 6;
    int v = (t < NB) ? bsum[t] : 0;
    int x = v;
    #pragma unroll
    for (int o = 1; o < 64; o <<= 1) {
        int y = __shfl_up(x, o);
        if (lane >= o) x += y;
    }
    __shared__ int ws[4];
    if (lane == 63) ws[wave] = x;
    __syncthreads();
    int add = 0;
    for (int w = 0; w < wave; ++w) add += ws[w];
    x += add;
    if (t < NB) boff[t] = x - v;
    if (t == 255) offs[NN] = x;
}

__global__ __launch_bounds__(256) void k_scan_c(const int* __restrict__ counts,
                                                const int* __restrict__ boff,
                                                int* __restrict__ offs,
                                                int* __restrict__ cursor) {
    int i = blockIdx.x * 256 + threadIdx.x;
    const int lane = threadIdx.x & 63, wave = threadIdx.x >> 6;
    int v = (i < NN) ? counts[i] : 0;
    int x = v;
    #pragma unroll
    for (int o = 1; o < 64; o <<= 1) {
        int y = __shfl_up(x, o);
        if (lane >= o) x += y;
    }
    __shared__ int ws[4];
    if (lane == 63) ws[wave] = x;
    __syncthreads();
    int add = boff[blockIdx.x];
    for (int w = 0; w < wave; ++w) add += ws[w];
    int ex = add + x - v;
    if (i < NN) {
        offs[i] = ex;
        cursor[i] = ex;
    }
}

// adj4 = {src, ea_bf16x2, att(f32, filled by k_att), dst}
__global__ __launch_bounds__(256) void k_scatter(const int* __restrict__ ei,
                                                 const float* __restrict__ ea,
                                                 int* __restrict__ cursor,
                                                 uint4* __restrict__ adj4) {
    int e = blockIdx.x * 256 + threadIdx.x;
    if (e >= EE) return;
    int d = ei[EE + e];
    int pos = atomicAdd(&cursor[d], 1);
    ushort lo = f2bf(ea[2 * e]);
    ushort hi = f2bf(ea[2 * e + 1]);
    adj4[pos] = make_uint4((uint)ei[e], ((uint)hi << 16) | (uint)lo, 0u, (uint)d);
}

// ---- K1: pqr = x @ Wc   [N,128]x[128,256] -> bf16 [N,256] -----------------
// 64 rows/block. Each wave holds its 16 B-fragments (4 col-tiles x 4 k) in
// registers, reused across 4 row-tiles -> 64 MFMA per wave per B-load.

__global__ __launch_bounds__(256) void k1_gemm(const float* __restrict__ xin,
                                               const ushort* __restrict__ wcT,
                                               ushort* __restrict__ pqr) {
    const int wave = threadIdx.x >> 6;
    const int lane = threadIdx.x & 63;
    const int rbase = blockIdx.x * 64;
    const int c0 = wave * 64;
    const int lrow = lane & 15;
    const int kg = lane >> 4;

    short8 b[4][4];
    #pragma unroll
    for (int t = 0; t < 4; ++t) {
        const int col = c0 + t * 16 + lrow;
        #pragma unroll
        for (int s = 0; s < 4; ++s)
            b[t][s] = *(const short8*)(wcT + col * 128 + s * 32 + kg * 8);
    }

    #pragma unroll
    for (int rt = 0; rt < 4; ++rt) {
        const int r0 = rbase + rt * 16;
        int arow = r0 + lrow;
        if (arow >= NN) arow = NN - 1;
        const float* xrow = xin + (size_t)arow * 128;
        short8 a[4];
        #pragma unroll
        for (int s = 0; s < 4; ++s) {
            const float* px = xrow + s * 32 + kg * 8;
            float4 u = *(const float4*)(px);
            float4 v = *(const float4*)(px + 4);
            short8 av;
            av[0] = (short)f2bf(u.x); av[1] = (short)f2bf(u.y);
            av[2] = (short)f2bf(u.z); av[3] = (short)f2bf(u.w);
            av[4] = (short)f2bf(v.x); av[5] = (short)f2bf(v.y);
            av[6] = (short)f2bf(v.z); av[7] = (short)f2bf(v.w);
            a[s] = av;
        }

        f32x4 acc[4] = {};
        #pragma unroll
        for (int t = 0; t < 4; ++t) {
            #pragma unroll
            for (int s = 0; s < 4; ++s)
                acc[t] = __builtin_amdgcn_mfma_f32_16x16x32_bf16(a[s], b[t][s], acc[t], 0, 0, 0);
        }
        #pragma unroll
        for (int t = 0; t < 4; ++t) {
            const int col = c0 + t * 16 + lrow;
            #pragma unroll
            for (int j = 0; j < 4; ++j) {
                const int orow = r0 + kg * 4 + j;
                if (orow < NN)
                    pqr[(size_t)orow * 256 + col] = f2bf(acc[t][j]);
            }
        }
    }
}

// ---- K_att: edge-parallel attention scores via MFMA -----------------------
// One wave = 64 edges = 4 MFMA tiles sharing one B fragment (col0 = w2).
// Reads adj4 {src,_,_,dst}; writes att into adj4[.].z (4B scattered stores).

__global__ __launch_bounds__(256) void k_att(uint4* __restrict__ adj4,
                                             const ushort* __restrict__ pqr,
                                             const float* __restrict__ b1v,
                                             const float* __restrict__ w2v,
                                             const float* __restrict__ b2v) {
    const int lane = threadIdx.x & 63;
    const int e0 = blockIdx.x * 256 + (threadIdx.x >> 6) * 64;
    const int row = lane & 15;
    const int kg = lane >> 4;
    const float b2 = b2v[0];

    short8 bv0, bv1;
    const bool col0 = (row == 0);
    #pragma unroll
    for (int j = 0; j < 8; ++j) {
        bv0[j] = (short)f2bf(col0 ? w2v[kg * 8 + j] : 0.f);
        bv1[j] = (short)f2bf(col0 ? w2v[32 + kg * 8 + j] : 0.f);
    }

    uint srcs[4], dsts[4];
    #pragma unroll
    for (int t = 0; t < 4; ++t) {
        const uint4 m = adj4[e0 + t * 16 + row];
        srcs[t] = m.x;
        dsts[t] = m.w;
    }

    f32x4 acc[4] = {};
    #pragma unroll
    for (int h = 0; h < 2; ++h) {
        const int cb = 32 * h + kg * 8;
        float4 bA = *(const float4*)(b1v + cb);
        float4 bB = *(const float4*)(b1v + cb + 4);
        const short8 bfrag = h ? bv1 : bv0;
        #pragma unroll
        for (int t = 0; t < 4; ++t) {
            short8 qv = *(const short8*)(pqr + (size_t)srcs[t] * 256 + 64 + cb);
            short8 pv = *(const short8*)(pqr + (size_t)dsts[t] * 256 + cb);
            short8 av;
            #pragma unroll
            for (int j = 0; j < 8; ++j) {
                float bb = (j < 4) ? ((const float*)&bA)[j] : ((const float*)&bB)[j - 4];
                float v = bf2f((ushort)qv[j]) + bf2f((ushort)pv[j]) + bb;
                av[j] = (short)f2bf_rn(fmaxf(v, 0.f));
            }
            acc[t] = __builtin_amdgcn_mfma_f32_16x16x32_bf16(av, bfrag, acc[t], 0, 0, 0);
        }
    }
    if (row == 0) {
        #pragma unroll
        for (int t = 0; t < 4; ++t) {
            #pragma unroll
            for (int j = 0; j < 4; ++j) {
                float s = acc[t][j] + b2;
                float att = 1.f / (1.f + __expf(-s));
                *(float*)((char*)(adj4 + e0 + t * 16 + kg * 4 + j) + 8) = att;
            }
        }
    }
}

// ---- K_msg: 1 wave/node, A/B-quad pipeline, zero rotation -----------------
// Per edge: ONE uint4 meta load + ONE 4B gather + 4 FMA. Tail handled by
// validity-select on att (wave-uniform cmp) against a zeroed 64-entry pad.

#define CONS(MM, RR, JJ)                                              \
    {                                                                 \
        const float a_ = ((JJ) < ee) ? __uint_as_float((MM).z) : 0.f; \
        acc0 = fmaf(a_, __uint_as_float((RR) << 16), acc0);           \
        acc1 = fmaf(a_, __uint_as_float((RR) & 0xffff0000u), acc1);   \
        sE0  = fmaf(a_, __uint_as_float((MM).y << 16), sE0);          \
        sE1  = fmaf(a_, __uint_as_float((MM).y & 0xffff0000u), sE1);  \
    }

#define LOADQ(M0, M1, M2, M3, R0, R1, R2, R3, BASE)          \
    {                                                        \
        M0 = adj4[(BASE)];                                   \
        M1 = adj4[(BASE) + 1];                               \
        M2 = adj4[(BASE) + 2];                               \
        M3 = adj4[(BASE) + 3];                               \
        R0 = *(const uint*)(rp + (size_t)M0.x * 256);        \
        R1 = *(const uint*)(rp + (size_t)M1.x * 256);        \
        R2 = *(const uint*)(rp + (size_t)M2.x * 256);        \
        R3 = *(const uint*)(rp + (size_t)M3.x * 256);        \
    }

__global__ __launch_bounds__(256) void k_msg(
    const int* __restrict__ offs, const uint4* __restrict__ adj4,
    const ushort* __restrict__ pqr, const float* __restrict__ xin,
    const float* __restrict__ web, const float* __restrict__ biasv,
    const float* __restrict__ gammav, const float* __restrict__ betav,
    float* __restrict__ xout, int do_relu) {
    const int lane = threadIdx.x & 63;
    const int n = blockIdx.x * 4 + (threadIdx.x >> 6);
    const int c0 = 2 * lane;

    const int eb = __builtin_amdgcn_readfirstlane(offs[n]);
    const int ee = __builtin_amdgcn_readfirstlane(offs[n + 1]);

    float acc0 = 0.f, acc1 = 0.f, sE0 = 0.f, sE1 = 0.f;
    if (eb < ee) {
        const ushort* rp = pqr + 128 + c0;
        uint4 a0, a1, a2, a3, b0, b1, b2, b3;
        uint ra0, ra1, ra2, ra3, rb0, rb1, rb2, rb3;
        LOADQ(a0, a1, a2, a3, ra0, ra1, ra2, ra3, eb);
        LOADQ(b0, b1, b2, b3, rb0, rb1, rb2, rb3, eb + 4);
        int j = eb;
        for (; j + 8 < ee; j += 8) {
            CONS(a0, ra0, j) CONS(a1, ra1, j + 1)
            CONS(a2, ra2, j + 2) CONS(a3, ra3, j + 3)
            LOADQ(a0, a1, a2, a3, ra0, ra1, ra2, ra3, j + 8);
            CONS(b0, rb0, j + 4) CONS(b1, rb1, j + 5)
            CONS(b2, rb2, j + 6) CONS(b3, rb3, j + 7)
            LOADQ(b0, b1, b2, b3, rb0, rb1, rb2, rb3, j + 12);
        }
        CONS(a0, ra0, j) CONS(a1, ra1, j + 1)
        CONS(a2, ra2, j + 2) CONS(a3, ra3, j + 3)
        CONS(b0, rb0, j + 4) CONS(b1, rb1, j + 5)
        CONS(b2, rb2, j + 6) CONS(b3, rb3, j + 7)
    }

    const float web00 = web[c0], web01 = web[c0 + 1];
    const float web10 = web[128 + c0], web11 = web[128 + c0 + 1];
    acc0 += sE0 * web00 + sE1 * web10;
    acc1 += sE0 * web01 + sE1 * web11;

    const float2 bi = *(const float2*)(biasv + c0);
    float v0 = acc0 + bi.x;
    float v1 = acc1 + bi.y;
    float sm = v0 + v1, sq = v0 * v0 + v1 * v1;
    #pragma unroll
    for (int o = 32; o > 0; o >>= 1) {
        sm += __shfl_xor(sm, o);
        sq += __shfl_xor(sq, o);
    }
    const float mean = sm * (1.f / 128.f);
    const float var = sq * (1.f / 128.f) - mean * mean;
    const float inv = rsqrtf(var + 1e-5f);
    const float2 ga = *(const float2*)(gammav + c0);
    const float2 be = *(const float2*)(betav + c0);
    float y0 = (v0 - mean) * inv * ga.x + be.x;
    float y1 = (v1 - mean) * inv * ga.y + be.y;
    if (do_relu) { y0 = fmaxf(y0, 0.f); y1 = fmaxf(y1, 0.f); }
    const float2 xr = *(const float2*)(xin + (size_t)n * 128 + c0);
    y0 += xr.x;
    y1 += xr.y;
    float2 o2; o2.x = y0; o2.y = y1;
    *(float2*)(xout + (size_t)n * 128 + c0) = o2;
}

// ---------------------------------------------------------------------------

extern "C" void kernel_launch(void* const* d_in, const int* in_sizes, int n_in,
                              void* d_out, int out_size, void* d_ws, size_t ws_size,
                              hipStream_t stream) {
    const float* x   = (const float*)d_in[0];
    const int*   ei  = (const int*)d_in[1];
    const float* ea  = (const float*)d_in[2];
    const float* wn  = (const float*)d_in[3];
    const float* wle = (const float*)d_in[4];
    const float* aw1 = (const float*)d_in[5];
    const float* ab1 = (const float*)d_in[6];
    const float* aw2 = (const float*)d_in[7];
    const float* ab2 = (const float*)d_in[8];
    const float* bia = (const float*)d_in[9];
    const float* gam = (const float*)d_in[10];
    const float* bet = (const float*)d_in[11];

    char* w = (char*)d_ws;
    size_t o = 0;
    auto alloc = [&](size_t bytes) {
        char* p = w + o;
        o = (o + bytes + 255) & ~(size_t)255;
        return p;
    };
    int*    counts = (int*)alloc((size_t)NN * 4);
    int*    offs   = (int*)alloc((size_t)(NN + 1) * 4);
    int*    cursor = (int*)alloc((size_t)NN * 4);
    int*    bsum   = (int*)alloc((size_t)NB * 4);
    int*    boff   = (int*)alloc((size_t)NB * 4);
    uint4*  adj4   = (uint4*)alloc((size_t)(EE + 64) * 16);
    ushort* wcT    = (ushort*)alloc((size_t)3 * 256 * 128 * 2);
    ushort* pqr    = (ushort*)alloc((size_t)NN * 256 * 2);
    float*  xb1    = (float*)alloc((size_t)NN * 128 * 4);
    float*  xb2    = (float*)alloc((size_t)NN * 128 * 4);

    hipMemsetAsync(counts, 0, (size_t)NN * 4, stream);
    hipMemsetAsync(adj4 + EE, 0, (size_t)64 * 16, stream);
    k_hist_compose<<<2500 + 384, 256, 0, stream>>>(ei, counts, wn, aw1, wle, wcT);
    k_scan_a<<<NB, 256, 0, stream>>>(counts, bsum);
    k_scan_b<<<1, 256, 0, stream>>>(bsum, boff, offs);
    k_scan_c<<<NB, 256, 0, stream>>>(counts, boff, offs, cursor);
    k_scatter<<<(EE + 255) / 256, 256, 0, stream>>>(ei, ea, cursor, adj4);

    const float* xi = x;
    float* xo = xb1;
    for (int l = 0; l < 3; ++l) {
        k1_gemm<<<(NN + 63) / 64, 256, 0, stream>>>(xi, wcT + (size_t)l * 256 * 128, pqr);
        k_att<<<EE / 256, 256, 0, stream>>>(adj4, pqr,
                                            ab1 + l * 64, aw2 + l * 64, ab2 + l);
        const bool last = (l == 2);
        float* out_ptr = last ? (float*)d_out : xo;
        k_msg<<<NN / 4, 256, 0, stream>>>(
            offs, adj4, pqr, xi,
            wle + ((size_t)l * 130 + 128) * 128,
            bia + l * 128, gam + l * 128, bet + l * 128,
            out_ptr, last ? 0 : 1);
        xi = out_ptr;
        xo = (l == 0) ? xb2 : xb1;
    }
}